// Round 1
// baseline (1401.348 us; speedup 1.0000x reference)
//
#include <hip/hip_runtime.h>
#include <hip/hip_bf16.h>

typedef unsigned short u16;
typedef __bf16 bf16x8 __attribute__((ext_vector_type(8)));
typedef float f32x4 __attribute__((ext_vector_type(4)));

#if __has_builtin(__builtin_amdgcn_exp2f)
#define EXP2F(x) __builtin_amdgcn_exp2f(x)
#else
#define EXP2F(x) exp2f(x)
#endif

// log2(e)/32  (softmax scale 1/sqrt(1024) folded into exp2 domain)
#define FA_C32 0.045084220027780106f

__device__ __forceinline__ f32x4 mfma16(bf16x8 a, bf16x8 b, f32x4 c) {
  return __builtin_amdgcn_mfma_f32_16x16x32_bf16(a, b, c, 0, 0, 0);
}
__device__ __forceinline__ unsigned pk2bf(float a, float b) {
  union { __bf16 h[2]; unsigned u; } x;
  x.h[0] = (__bf16)a; x.h[1] = (__bf16)b;
  return x.u;
}
__device__ __forceinline__ u16 bf1(float a) {
  union { __bf16 h; u16 u; } x; x.h = (__bf16)a; return x.u;
}

typedef __attribute__((address_space(1))) const unsigned int gas_u32;
typedef __attribute__((address_space(3))) unsigned int las_u32;
__device__ __forceinline__ void gl_lds16(const u16* g, u16* l) {
  __builtin_amdgcn_global_load_lds((gas_u32*)g, (las_u32*)l, 16, 0, 0);
}

// ---------------- cast fp32 -> bf16, 8 elems/thread ----------------
__global__ __launch_bounds__(256) void cast_bf16_k(const float* __restrict__ src,
                                                   u16* __restrict__ dst, int n8) {
  int i = blockIdx.x * 256 + threadIdx.x;
  if (i >= n8) return;
  const float4* s4 = (const float4*)src;
  float4 a = s4[i * 2], b = s4[i * 2 + 1];
  uint4 o;
  o.x = pk2bf(a.x, a.y); o.y = pk2bf(a.z, a.w);
  o.z = pk2bf(b.x, b.y); o.w = pk2bf(b.z, b.w);
  ((uint4*)dst)[i] = o;
}

// ---------------- QKV projection GEMM (m97-structure) ----------------
// C[m,n] = sum_k Xb[m,k]*Wb[n,k] + bias[n];  M=16384 N=3072 K=1024
// n in [0,1024) -> Q row-major; [1024,2048) -> K row-major; [2048,3072) -> V transposed Vt[b][d][s]
__global__ __launch_bounds__(256) void gemm_qkv(const u16* __restrict__ Xb,
    const u16* __restrict__ Wb, const float* __restrict__ bias,
    u16* __restrict__ Qo, u16* __restrict__ Ko, u16* __restrict__ Vt) {
  __shared__ u16 As[128 * 64];
  __shared__ u16 Bs[128 * 64];
  const int tid = threadIdx.x, lane = tid & 63, w = tid >> 6;
  const int m0 = blockIdx.x * 128, n0 = blockIdx.y * 128;
  const int wr = w >> 1, wc = w & 1;

  f32x4 acc[4][4];
#pragma unroll
  for (int i = 0; i < 4; ++i)
#pragma unroll
    for (int j = 0; j < 4; ++j) acc[i][j] = 0.f;

  // staging: chunk c = w*4+i covers 8 rows; lane -> row c*8+(lane>>3), k (lane&7)*8
  const int srow = w * 32 + (lane >> 3);
  const int skol = (lane & 7) * 8;
  const u16* ag = Xb + (size_t)(m0 + srow) * 1024 + skol;
  const u16* bg = Wb + (size_t)(n0 + srow) * 1024 + skol;
  u16* as_l = As + (w * 4) * 512;
  u16* bs_l = Bs + (w * 4) * 512;

  for (int kt = 0; kt < 16; ++kt) {
    __syncthreads();
#pragma unroll
    for (int i = 0; i < 4; ++i) {
      gl_lds16(ag + i * 8 * 1024 + kt * 64, as_l + i * 512);
      gl_lds16(bg + i * 8 * 1024 + kt * 64, bs_l + i * 512);
    }
    __syncthreads();
#pragma unroll
    for (int kc = 0; kc < 2; ++kc) {
      bf16x8 af[4], bfr[4];
#pragma unroll
      for (int rf = 0; rf < 4; ++rf)
        af[rf] = *(const bf16x8*)(As + (wr * 64 + rf * 16 + (lane & 15)) * 64 + kc * 32 + (lane >> 4) * 8);
#pragma unroll
      for (int cf = 0; cf < 4; ++cf)
        bfr[cf] = *(const bf16x8*)(Bs + (wc * 64 + cf * 16 + (lane & 15)) * 64 + kc * 32 + (lane >> 4) * 8);
#pragma unroll
      for (int rf = 0; rf < 4; ++rf)
#pragma unroll
        for (int cf = 0; cf < 4; ++cf)
          acc[rf][cf] = mfma16(af[rf], bfr[cf], acc[rf][cf]);
    }
  }

  // epilogue: bias + bf16 store
  float bv[4];
#pragma unroll
  for (int cf = 0; cf < 4; ++cf) bv[cf] = bias[n0 + wc * 64 + cf * 16 + (lane & 15)];
  const int region = n0 >> 10;              // 0=Q 1=K 2=V
  const int ncol = (n0 & 1023) + wc * 64;
  if (region < 2) {
    u16* dst = region ? Ko : Qo;
#pragma unroll
    for (int rf = 0; rf < 4; ++rf) {
      int m = m0 + wr * 64 + rf * 16 + (lane >> 4) * 4;
#pragma unroll
      for (int r = 0; r < 4; ++r)
#pragma unroll
        for (int cf = 0; cf < 4; ++cf)
          dst[(size_t)(m + r) * 1024 + ncol + cf * 16 + (lane & 15)] = bf1(acc[rf][cf][r] + bv[cf]);
    }
  } else {
#pragma unroll
    for (int rf = 0; rf < 4; ++rf) {
      int m = m0 + wr * 64 + rf * 16 + (lane >> 4) * 4;
      int bb = m >> 12, s = m & 4095;
#pragma unroll
      for (int cf = 0; cf < 4; ++cf) {
        int d = ncol + cf * 16 + (lane & 15);
        uint2 v;
        v.x = pk2bf(acc[rf][cf][0] + bv[cf], acc[rf][cf][1] + bv[cf]);
        v.y = pk2bf(acc[rf][cf][2] + bv[cf], acc[rf][cf][3] + bv[cf]);
        *(uint2*)&Vt[(size_t)(bb * 1024 + d) * 4096 + s] = v;
      }
    }
  }
}

// ---------------- flash attention: BQ=64, BK=128, 8 waves ----------------
// QK^T swapped (mfma(K,Q) -> D[key][q]); online softmax (exp2 domain); PV split by d.
__global__ __launch_bounds__(512) void flash_k(const u16* __restrict__ Qg,
    const u16* __restrict__ Kg, const u16* __restrict__ Vtg,
    float* __restrict__ Og) {
  __shared__ u16 Qs[64 * 1024];     // 128 KiB, XOR-swizzled (G4: D=1024 row-major = 32-way conflict)
  __shared__ u16 Ps[64 * 128];      // 16 KiB, swizzled
  __shared__ float m2s[64], ls[64], cs[64], pmaxp[2][64], lsump[2][64];
  __shared__ int allc1;

  const int tid = threadIdx.x, lane = tid & 63, wid = tid >> 6;
  const int bid = blockIdx.x;
  // XCD-aware: 2 XCDs per batch, 32 contiguous qblks per XCD -> K/V tile L2-resident
  const int xcd = bid & 7, idx = bid >> 3;
  const int batch = xcd >> 1, qblk = (xcd & 1) * 32 + idx;
  const u16* Qp = Qg + (size_t)(batch * 4096 + qblk * 64) * 1024;
  const u16* Kp = Kg + (size_t)batch * 4096 * 1024;
  const u16* Vp = Vtg + (size_t)batch * 1024 * 4096;
  float* Op = Og + (size_t)(batch * 4096 + qblk * 64) * 1024;

  // stage Q into swizzled LDS
#pragma unroll
  for (int i = 0; i < 16; ++i) {
    int c = i * 512 + tid;
    int row = c >> 7, h8 = c & 127;
    uint4 v = *(const uint4*)(Qp + row * 1024 + h8 * 8);
    *(uint4*)((char*)Qs + ((row * 2048 + h8 * 16) ^ ((row & 7) << 4))) = v;
  }
  if (tid < 64) { m2s[tid] = -1e30f; ls[tid] = 0.f; }

  f32x4 O[4][8];
#pragma unroll
  for (int a = 0; a < 4; ++a)
#pragma unroll
    for (int d = 0; d < 8; ++d) O[a][d] = 0.f;

  const int qg = wid & 3, kg = wid >> 2;   // QK role: 4 qgroups x 2 keygroups
  const int dw = wid * 128;                // PV role: d-slice per wave
  const int qrow = qg * 16 + (lane & 15);
  const int qb_base = qrow * 2048 + (lane >> 4) * 16;
  const int qswz = (qrow & 7) << 4;
  __syncthreads();

  for (int t = 0; t < 32; ++t) {
    // ---- QK^T ----
    const int kbase = t * 128 + kg * 64;
    f32x4 Sv[4];
#pragma unroll
    for (int kt = 0; kt < 4; ++kt) Sv[kt] = 0.f;
    const u16* kp0 = Kp + (size_t)(kbase + (lane & 15)) * 1024 + (lane >> 4) * 8;
    bf16x8 ka[2][4];
#pragma unroll
    for (int kt = 0; kt < 4; ++kt) ka[0][kt] = *(const bf16x8*)(kp0 + kt * 16 * 1024);
#pragma unroll
    for (int kc = 0; kc < 32; ++kc) {
      const int cur = kc & 1;
      if (kc < 31) {
#pragma unroll
        for (int kt = 0; kt < 4; ++kt)
          ka[cur ^ 1][kt] = *(const bf16x8*)(kp0 + kt * 16 * 1024 + (kc + 1) * 32);
      }
      bf16x8 qf = *(const bf16x8*)((const char*)Qs + ((qb_base + kc * 64) ^ qswz));
#pragma unroll
      for (int kt = 0; kt < 4; ++kt) Sv[kt] = mfma16(ka[cur][kt], qf, Sv[kt]);
    }

    // per-q-col max over this wave's 64 keys
    float pm = Sv[0][0];
#pragma unroll
    for (int kt = 0; kt < 4; ++kt)
#pragma unroll
      for (int r = 0; r < 4; ++r) pm = fmaxf(pm, Sv[kt][r]);
    pm = fmaxf(pm, __shfl_xor(pm, 16, 64));
    pm = fmaxf(pm, __shfl_xor(pm, 32, 64));

    __syncthreads();                       // barA: prev PV done with Ps/cs
    if (lane < 16) pmaxp[kg][qg * 16 + lane] = pm;
    __syncthreads();                       // barB
    if (tid < 64) {
      float mt = fmaxf(pmaxp[0][tid], pmaxp[1][tid]) * FA_C32;
      float mo = m2s[tid];
      float mn = fmaxf(mo, mt);
      float c = EXP2F(mo - mn);
      cs[tid] = c;
      m2s[tid] = mn;
      int f = __all(c == 1.0f);
      if (tid == 0) allc1 = f;
    }
    __syncthreads();                       // barC
    {
      float mrow = m2s[qrow];
      float lsum = 0.f;
#pragma unroll
      for (int kt = 0; kt < 4; ++kt) {
        float p0 = EXP2F(Sv[kt][0] * FA_C32 - mrow);
        float p1 = EXP2F(Sv[kt][1] * FA_C32 - mrow);
        float p2 = EXP2F(Sv[kt][2] * FA_C32 - mrow);
        float p3 = EXP2F(Sv[kt][3] * FA_C32 - mrow);
        lsum += (p0 + p1) + (p2 + p3);
        uint2 pv;
        pv.x = pk2bf(p0, p1);
        pv.y = pk2bf(p2, p3);
        int key = kg * 64 + kt * 16 + (lane >> 4) * 4;
        *(uint2*)((char*)Ps + ((qrow * 256 + key * 2) ^ qswz)) = pv;
      }
      lsum += __shfl_xor(lsum, 16, 64);
      lsum += __shfl_xor(lsum, 32, 64);
      if (lane < 16) lsump[kg][qg * 16 + lane] = lsum;
    }
    __syncthreads();                       // barD: Ps/cs/flag ready
    if (tid < 64) ls[tid] = ls[tid] * cs[tid] + lsump[0][tid] + lsump[1][tid];

    // ---- PV ----
    if (!allc1) {
#pragma unroll
      for (int rf = 0; rf < 4; ++rf)
#pragma unroll
        for (int r = 0; r < 4; ++r) {
          float c = cs[rf * 16 + (lane >> 4) * 4 + r];
#pragma unroll
          for (int dt = 0; dt < 8; ++dt) O[rf][dt][r] *= c;
        }
    }
    const u16* vp0 = Vp + (size_t)(dw + (lane & 15)) * 4096 + t * 128 + (lane >> 4) * 8;
#pragma unroll
    for (int kc = 0; kc < 4; ++kc) {
      bf16x8 pa[4];
#pragma unroll
      for (int rf = 0; rf < 4; ++rf) {
        int prow = rf * 16 + (lane & 15);
        pa[rf] = *(const bf16x8*)((const char*)Ps + ((prow * 256 + kc * 64 + (lane >> 4) * 16) ^ ((prow & 7) << 4)));
      }
#pragma unroll
      for (int dt = 0; dt < 8; ++dt) {
        bf16x8 vf = *(const bf16x8*)(vp0 + dt * 16 * 4096 + kc * 32);
#pragma unroll
        for (int rf = 0; rf < 4; ++rf) O[rf][dt] = mfma16(pa[rf], vf, O[rf][dt]);
      }
    }
  }

  __syncthreads();                         // ls final
#pragma unroll
  for (int rf = 0; rf < 4; ++rf)
#pragma unroll
    for (int r = 0; r < 4; ++r) {
      int row = rf * 16 + (lane >> 4) * 4 + r;
      float linv = 1.0f / ls[row];
#pragma unroll
      for (int dt = 0; dt < 8; ++dt)
        Op[(size_t)row * 1024 + dw + dt * 16 + (lane & 15)] = O[rf][dt][r] * linv;
    }
}

// ---------------- host ----------------
extern "C" void kernel_launch(void* const* d_in, const int* in_sizes, int n_in,
                              void* d_out, int out_size, void* d_ws, size_t ws_size,
                              hipStream_t stream) {
  const float* X = (const float*)d_in[0];   // [4,4096,1024]
  const float* W = (const float*)d_in[1];   // [3072,1024]
  const float* b = (const float*)d_in[2];   // [3072]
  float* out = (float*)d_out;               // [4,4096,1024] fp32
  char* ws = (char*)d_ws;
  // ws layout (needs 140,509,184 B):
  u16* Xb = (u16*)(ws);                     // 33,554,432
  u16* Wb = (u16*)(ws + 33554432);          //  6,291,456
  u16* Qb = (u16*)(ws + 39845888);          // 33,554,432
  u16* Kb = (u16*)(ws + 73400320);          // 33,554,432
  u16* Vt = (u16*)(ws + 106954752);         // 33,554,432 (V transposed [4][1024][4096])

  cast_bf16_k<<<8192, 256, 0, stream>>>(X, Xb, 16777216 / 8);
  cast_bf16_k<<<1536, 256, 0, stream>>>(W, Wb, 3145728 / 8);
  dim3 gg(128, 24);
  gemm_qkv<<<gg, 256, 0, stream>>>(Xb, Wb, b, Qb, Kb, Vt);
  flash_k<<<256, 512, 0, stream>>>(Qb, Kb, Vt, out);
}